// Round 4
// baseline (152.110 us; speedup 1.0000x reference)
//
#include <hip/hip_runtime.h>

#define TT 2048
#define DD 384

typedef float f32x4 __attribute__((ext_vector_type(4)));
typedef float f32x16 __attribute__((ext_vector_type(16)));
typedef short s16x8 __attribute__((ext_vector_type(8)));
typedef short s16x2 __attribute__((ext_vector_type(2)));
typedef unsigned int u32x4 __attribute__((ext_vector_type(4)));

typedef __attribute__((address_space(3))) unsigned char* as3p;
typedef const __attribute__((address_space(1))) unsigned char* as1p;
// HW direct global->LDS copy: 16B/lane x 64 lanes = 1KB per call; LDS dest = uniform base + lane*16.
#define GLLDS(gsrc, ldst) __builtin_amdgcn_global_load_lds((as1p)(gsrc), (as3p)(ldst), 16, 0, 0)

static __device__ __forceinline__ unsigned short f2bf(float f) {
    unsigned int u = __builtin_bit_cast(unsigned int, f);
    u = (u + 0x7fffu + ((u >> 16) & 1u)) >> 16;
    return (unsigned short)u;
}
static __device__ __forceinline__ unsigned int pk2(float a, float b) {
#if __has_builtin(__builtin_amdgcn_cvt_pk_bf16_f32)
    s16x2 t = __builtin_amdgcn_cvt_pk_bf16_f32(a, b);
    return __builtin_bit_cast(unsigned int, t);
#else
    unsigned int ua = __builtin_bit_cast(unsigned int, a);
    unsigned int ub = __builtin_bit_cast(unsigned int, b);
    ua = (ua + 0x7fffu + ((ua >> 16) & 1u)) >> 16;
    ub = (ub + 0x7fffu + ((ub >> 16) & 1u)) & 0xffff0000u;
    return ua | ub;
#endif
}

// ---------------- prep: x -> bf16 pre-swizzled LDS-image; W -> bf16 col-major pre-swizzled ----------
// xbf[m][k]: within each 32-k group, 8-elt chunk c stored at c^(m&3). Identical image to the GEMM's
// A-tile LDS layout, so qkv_gemm can global_load_lds it verbatim (no VALU, no fp32 re-reads).
// wall[col][k]: col 0..63=Wq, 64..127=Wk, 128..511=Wv columns; same swizzle with key (col&3).
__global__ __launch_bounds__(256, 8) void xwprep(
    const float* __restrict__ x, const float* __restrict__ Wq,
    const float* __restrict__ Wk, const float* __restrict__ Wv,
    unsigned short* __restrict__ xbf, unsigned short* __restrict__ wall)
{
    const int gid = blockIdx.x * 256 + threadIdx.x;
    if (gid < 196608) {                       // x: 16384 rows x 12 k-groups
        const int kt = gid >> 14;
        const int m  = gid & 16383;
        const float* xp = x + (size_t)m * 384 + kt * 32;
        unsigned short* op = xbf + (size_t)m * 384 + kt * 32;
        #pragma unroll
        for (int c = 0; c < 4; ++c) {
            f32x4 a = *(const f32x4*)(xp + c * 8);
            f32x4 b = *(const f32x4*)(xp + c * 8 + 4);
            s16x8 v;
            v[0] = (short)f2bf(a[0]); v[1] = (short)f2bf(a[1]);
            v[2] = (short)f2bf(a[2]); v[3] = (short)f2bf(a[3]);
            v[4] = (short)f2bf(b[0]); v[5] = (short)f2bf(b[1]);
            v[6] = (short)f2bf(b[2]); v[7] = (short)f2bf(b[3]);
            *(s16x8*)(op + ((c ^ (m & 3)) * 8)) = v;
        }
    } else {                                  // W: 512 cols x 12 k-groups
        const int gid2 = gid - 196608;        // 0..6143
        const int col = gid2 & 511;
        const int kt  = gid2 >> 9;
        unsigned short* op = wall + (size_t)col * 384 + kt * 32;
        #pragma unroll
        for (int c = 0; c < 4; ++c) {
            s16x8 v;
            #pragma unroll
            for (int k7 = 0; k7 < 8; ++k7) {
                const int k = kt * 32 + c * 8 + k7;
                float f = (col < 64)  ? Wq[(size_t)k * 64 + col]
                        : (col < 128) ? Wk[(size_t)k * 64 + (col - 64)]
                                      : Wv[(size_t)k * 384 + (col - 128)];
                v[k7] = (short)f2bf(f);
            }
            *(s16x8*)(op + ((c ^ (col & 3)) * 8)) = v;
        }
    }
}

// ---------------- fused QKV projection GEMM v2: all-GLLDS staging, dbuf, single barrier ----------
// A and B arrive pre-swizzled bf16 from xwprep -> staging is 16 global_load_lds calls per kt,
// zero conversion VALU in the loop. Outputs unchanged: q natural (scaled 1/8), k pre-swizzled,
// vT transposed pre-swizzled (verbatim images for the attn kernel).
__global__ __launch_bounds__(256, 4) void qkv_gemm(
    const unsigned short* __restrict__ xbf, const unsigned short* __restrict__ wall,
    unsigned short* __restrict__ qo, unsigned short* __restrict__ ko,
    unsigned short* __restrict__ vto)
{
    __shared__ __align__(16) unsigned short lds[16384];   // 2 bufs x (A 8KB | B 8KB)
    const int tid = threadIdx.x;
    const int l   = tid & 63;
    const int w   = tid >> 6;
    const int si  = l & 15;
    const int qq  = l >> 4;
    const int m0  = blockIdx.x * 128;
    const int nb  = blockIdx.y;
    const int wr  = w >> 1, wc = w & 1;

    const unsigned short* asrc = xbf + ((size_t)m0 + (l >> 2)) * 384 + (l & 3) * 8;
    const unsigned short* bsrc = wall + ((size_t)(nb * 128) + (l >> 2)) * 384 + (l & 3) * 8;

#define QSTAGE(KT, B)                                                                     \
    {                                                                                     \
        _Pragma("unroll")                                                                 \
        for (int i = 0; i < 2; ++i) {                                                     \
            const int u = w * 2 + i;                                                      \
            GLLDS(asrc + (size_t)(u * 16) * 384 + (KT) * 32, &lds[(B) * 8192 + u * 512]); \
            GLLDS(bsrc + (size_t)(u * 16) * 384 + (KT) * 32, &lds[(B) * 8192 + 4096 + u * 512]); \
        }                                                                                 \
    }

    f32x4 acc[4][4];
    #pragma unroll
    for (int rt = 0; rt < 4; ++rt)
        #pragma unroll
        for (int ct = 0; ct < 4; ++ct) acc[rt][ct] = (f32x4){0.f, 0.f, 0.f, 0.f};

    QSTAGE(0, 0);
    for (int kt = 0; kt < 12; ++kt) {
        const int b = kt & 1;
        __syncthreads();                       // vmcnt(0)+barrier: buf b staged; other buf free
        if (kt < 11) QSTAGE(kt + 1, 1 - b);

        s16x8 af[4], bf[4];
        #pragma unroll
        for (int rt = 0; rt < 4; ++rt) {
            const int row = wr * 64 + rt * 16 + si;
            af[rt] = *(const s16x8*)&lds[b * 8192 + row * 32 + ((qq ^ (row & 3)) * 8)];
        }
        #pragma unroll
        for (int ct = 0; ct < 4; ++ct) {
            const int col = wc * 64 + ct * 16 + si;
            bf[ct] = *(const s16x8*)&lds[b * 8192 + 4096 + col * 32 + ((qq ^ (col & 3)) * 8)];
        }
        #pragma unroll
        for (int rt = 0; rt < 4; ++rt)
            #pragma unroll
            for (int ct = 0; ct < 4; ++ct)
                acc[rt][ct] = __builtin_amdgcn_mfma_f32_16x16x32_bf16(af[rt], bf[ct], acc[rt][ct], 0, 0, 0);
    }
    __syncthreads();                           // before epilogue reuses LDS
#undef QSTAGE

    if (nb == 0) {
        if (wc == 0) {  // q: natural layout, fold 1/sqrt(K)
            #pragma unroll
            for (int rt = 0; rt < 4; ++rt)
                #pragma unroll
                for (int ct = 0; ct < 4; ++ct)
                    #pragma unroll
                    for (int r = 0; r < 4; ++r) {
                        const int m = m0 + wr * 64 + rt * 16 + qq * 4 + r;
                        qo[(size_t)m * 64 + ct * 16 + si] = f2bf(acc[rt][ct][r] * 0.125f);
                    }
        } else {        // k: pre-swizzled (chunk c -> c ^ (t&7))
            #pragma unroll
            for (int rt = 0; rt < 4; ++rt)
                #pragma unroll
                for (int ct = 0; ct < 4; ++ct)
                    #pragma unroll
                    for (int r = 0; r < 4; ++r) {
                        const int m = m0 + wr * 64 + rt * 16 + qq * 4 + r;
                        const int col = ct * 16 + si;
                        ko[(size_t)m * 64 + (((col >> 3) ^ (m & 7)) * 8) + (col & 7)] = f2bf(acc[rt][ct][r]);
                    }
        }
    } else {
        #pragma unroll
        for (int rt = 0; rt < 4; ++rt)
            #pragma unroll
            for (int ct = 0; ct < 4; ++ct)
                #pragma unroll
                for (int r = 0; r < 4; ++r) {
                    const int m = wr * 64 + rt * 16 + qq * 4 + r;
                    const int n = wc * 64 + ct * 16 + si;
                    lds[n * 128 + (((m >> 3) ^ (n & 7)) * 8) + (m & 7)] = f2bf(acc[rt][ct][r]);
                }
        __syncthreads();
        const int bbat = m0 >> 11, t0 = m0 & 2047;
        #pragma unroll
        for (int i = 0; i < 8; ++i) {
            const int u = tid + 256 * i, n = u >> 4, mc = u & 15;
            s16x8 v = *(const s16x8*)&lds[n * 128 + ((mc ^ (n & 7)) * 8)];
            *(s16x8*)&vto[((size_t)bbat * DD + ((nb - 1) * 128 + n)) * TT
                          + t0 + (mc >> 3) * 64 + (((mc & 7) ^ (n & 7)) * 8)] = v;
        }
    }
}

// ---------------- fused causal attention v2: producer/consumer wave specialization ----------------
// Same 80KB LDS image + lag-1 P pipeline + 1 barrier/iter as R3, but waves are SPECIALIZED:
// waves 0,1 = PRODUCERS (s-subtile ri: QK MFMA + exp + pack for BOTH qh; stage K), waves 2,3 =
// CONSUMERS (e-half ri: 16 PV MFMAs across both qh from pl[it-1]; stage V). Per-iteration period
// becomes max(produce, consume) instead of their sum; arithmetic order per row is unchanged.
__global__ __launch_bounds__(256, 2) void attn(
    const unsigned short* __restrict__ qg, const unsigned short* __restrict__ kg,
    const unsigned short* __restrict__ vg, float* __restrict__ out)
{
    // ush map: kl [0,8192) = 2 x [64 t][64] | vl [8192,32768) = 3 x [128 e][64 t]
    //          pl [32768,40960) = 2 x [2 qh][2 sc][a0:512|a1:512] | stL overlays kl after loop
    __shared__ __align__(16) unsigned short lds[40960];

    const int tid = threadIdx.x;
    const int l   = tid & 63;
    const int w   = tid >> 6;      // 0,1 producers; 2,3 consumers
    const int ri  = w & 1;         // producer: s-subtile; consumer: 64-e col group
    const int prod = (w < 2);
    const int lo  = l & 31;
    const int hi  = l >> 5;

    const int g    = blockIdx.x;          // 0..767
    const int bb   = g & 7;
    const int rest = g >> 3;              // 0..95
    const int eh   = rest % 3;
    const int q2   = 31 - rest / 3;       // descending work (LPT)
    const int q0   = q2 * 64;
    const int e0   = eh * 128;

    // producers: Q frags for BOTH 32-row halves (pre-scaled 1/8, natural layout)
    s16x8 qf2[2][4];
    if (prod) {
        #pragma unroll
        for (int qh = 0; qh < 2; ++qh) {
            const unsigned short* qp = qg + ((size_t)bb * TT + q0 + qh * 32 + lo) * 64;
            #pragma unroll
            for (int st = 0; st < 4; ++st) qf2[qh][st] = *(const s16x8*)(qp + st * 16 + hi * 8);
        }
    }

    f32x16 o4[2][2];                       // consumers: [qh][et] 32q x 32e each
    #pragma unroll
    for (int qh = 0; qh < 2; ++qh)
        #pragma unroll
        for (int et = 0; et < 2; ++et)
            #pragma unroll
            for (int r = 0; r < 16; ++r) o4[qh][et][r] = 0.f;
    float lp2[2] = {0.f, 0.f};             // producers: row-sum partials per qh

    const unsigned short* kbase = kg + (size_t)bb * TT * 64;
    const unsigned short* vbase = vg + ((size_t)bb * DD + e0) * TT;

    // staging split by role: producers 4 K-chunks each, consumers 8 V-chunks each (1KB per call)
#define STAGE(IT, KB, VB)                                                                  \
    {                                                                                      \
        if (prod) {                                                                        \
            _Pragma("unroll")                                                              \
            for (int c4 = 0; c4 < 4; ++c4) {                                               \
                const int ch = w * 4 + c4;                                                 \
                GLLDS(kbase + (size_t)(IT) * 4096 + ch * 512 + l * 8,                      \
                      &lds[(KB) * 4096 + ch * 512]);                                       \
            }                                                                              \
        } else {                                                                           \
            _Pragma("unroll")                                                              \
            for (int c8 = 0; c8 < 8; ++c8) {                                               \
                const int rg = ri * 8 + c8;                                                \
                GLLDS(vbase + (size_t)(rg * 8 + (l >> 3)) * TT + (IT) * 64 + (l & 7) * 8,  \
                      &lds[8192 + (VB) * 8192 + rg * 512]);                                \
            }                                                                              \
        }                                                                                  \
    }

    // consumer PV step for one s-tile from vl[VB], pl[PB]: both qh, both sc, this wave's 64 e
#define PVC(VB, PB)                                                                        \
    {                                                                                      \
        _Pragma("unroll")                                                                  \
        for (int s2 = 0; s2 < 2; ++s2) {                                                   \
            const int pbse = 32768 + (PB) * 4096 + s2 * 1024;                              \
            s16x8 a00 = *(const s16x8*)&lds[pbse + l * 8];                                 \
            s16x8 a01 = *(const s16x8*)&lds[pbse + 512 + l * 8];                           \
            s16x8 a10 = *(const s16x8*)&lds[pbse + 2048 + l * 8];                          \
            s16x8 a11 = *(const s16x8*)&lds[pbse + 2560 + l * 8];                          \
            _Pragma("unroll")                                                              \
            for (int et = 0; et < 2; ++et) {                                               \
                const int el = ri * 64 + et * 32 + lo;                                     \
                const int vbse = 8192 + (VB) * 8192 + el * 64;                             \
                s16x8 v0 = *(const s16x8*)&lds[vbse + (((s2 * 4 + hi) ^ (el & 7)) * 8)];   \
                s16x8 v1 = *(const s16x8*)&lds[vbse + (((s2 * 4 + 2 + hi) ^ (el & 7)) * 8)]; \
                o4[0][et] = __builtin_amdgcn_mfma_f32_32x32x16_bf16(a00, v0, o4[0][et], 0, 0, 0); \
                o4[0][et] = __builtin_amdgcn_mfma_f32_32x32x16_bf16(a01, v1, o4[0][et], 0, 0, 0); \
                o4[1][et] = __builtin_amdgcn_mfma_f32_32x32x16_bf16(a10, v0, o4[1][et], 0, 0, 0); \
                o4[1][et] = __builtin_amdgcn_mfma_f32_32x32x16_bf16(a11, v1, o4[1][et], 0, 0, 0); \
            }                                                                              \
        }                                                                                  \
    }

    STAGE(0, 0, 0);   // prologue: tile 0 -> kl0 / vl0

    int vi = 0, vn = 1;   // vl slot of tile it, it+1 (mod 3); tile it-1 sits at the third slot
    for (int it = 0; it <= q2; ++it) {
        const int kb = it & 1;
        __syncthreads();   // vmcnt(0)+barrier: staging for tile it complete; pl[kb] free

        if (it < q2) STAGE(it + 1, 1 - kb, vn);   // in flight through the whole compute phase

        if (prod) {
            const bool mb = (it == q2);
            s16x8 kfr[4];
            #pragma unroll
            for (int st = 0; st < 4; ++st)
                kfr[st] = *(const s16x8*)&lds[kb * 4096 + (ri * 32 + lo) * 64 + (((st * 2 + hi) ^ (lo & 7)) * 8)];
            #pragma unroll
            for (int qh = 0; qh < 2; ++qh) {
                const int qrow = q0 + qh * 32 + lo;
                f32x16 sa;
                #pragma unroll
                for (int r = 0; r < 16; ++r) sa[r] = 0.f;
                #pragma unroll
                for (int st = 0; st < 4; ++st)
                    sa = __builtin_amdgcn_mfma_f32_32x32x16_bf16(kfr[st], qf2[qh][st], sa, 0, 0, 0);
                float pv[16];
                #pragma unroll
                for (int r = 0; r < 16; ++r) {
                    float e = __expf(sa[r]);
                    if (mb) {
                        const int srow = it * 64 + ri * 32 + (r & 3) + 8 * (r >> 2) + 4 * hi;
                        if (srow > qrow) e = 0.f;
                    }
                    pv[r] = e;
                    lp2[qh] += e;
                }
                unsigned int d0 = pk2(pv[0], pv[1]),   d1 = pk2(pv[2], pv[3]);
                unsigned int d2 = pk2(pv[4], pv[5]),   d3 = pk2(pv[6], pv[7]);
                unsigned int d4 = pk2(pv[8], pv[9]),   d5 = pk2(pv[10], pv[11]);
                unsigned int d6 = pk2(pv[12], pv[13]), d7 = pk2(pv[14], pv[15]);
                unsigned int sA0 = hi ? d0 : d2, sA1 = hi ? d1 : d3;
                unsigned int rA0 = (unsigned int)__shfl_xor((int)sA0, 32);
                unsigned int rA1 = (unsigned int)__shfl_xor((int)sA1, 32);
                u32x4 fa0 = hi ? (u32x4){rA0, rA1, d2, d3} : (u32x4){d0, d1, rA0, rA1};
                unsigned int sB0 = hi ? d4 : d6, sB1 = hi ? d5 : d7;
                unsigned int rB0 = (unsigned int)__shfl_xor((int)sB0, 32);
                unsigned int rB1 = (unsigned int)__shfl_xor((int)sB1, 32);
                u32x4 fa1 = hi ? (u32x4){rB0, rB1, d6, d7} : (u32x4){d4, d5, rB0, rB1};
                *(s16x8*)&lds[32768 + kb * 4096 + (qh * 2 + ri) * 1024 + l * 8]       = __builtin_bit_cast(s16x8, fa0);
                *(s16x8*)&lds[32768 + kb * 4096 + (qh * 2 + ri) * 1024 + 512 + l * 8] = __builtin_bit_cast(s16x8, fa1);
            }
        } else if (it > 0) {
            const int vp = (vi == 0) ? 2 : vi - 1;
            PVC(vp, 1 - kb);
        }

        vi = vn; vn = (vn == 2) ? 0 : vn + 1;
    }
    __syncthreads();           // last pl writes visible; all staging reads done

    if (prod) {                // row totals -> stL (overlays dead kl region)
        #pragma unroll
        for (int qh = 0; qh < 2; ++qh) {
            float lp = lp2[qh] + __shfl_xor(lp2[qh], 32);
            if (hi == 0) ((float*)lds)[(qh * 2 + ri) * 32 + lo] = lp;
        }
    } else {                   // final PV for tile q2 (runs concurrently with stL writes)
        const int vlast = (vi == 0) ? 2 : vi - 1;
        PVC(vlast, q2 & 1);
    }
    __syncthreads();

    if (!prod) {
        const float* stL = (const float*)lds;
        #pragma unroll
        for (int qh = 0; qh < 2; ++qh)
            #pragma unroll
            for (int et = 0; et < 2; ++et)
                #pragma unroll
                for (int r = 0; r < 16; ++r) {
                    const int rloc = (r & 3) + 8 * (r >> 2) + 4 * hi;
                    const float linv = 1.f / (stL[qh * 64 + rloc] + stL[qh * 64 + 32 + rloc]);
                    out[((size_t)bb * TT + q0 + qh * 32 + rloc) * DD + e0 + ri * 64 + et * 32 + lo]
                        = o4[qh][et][r] * linv;
                }
    }
#undef STAGE
#undef PVC
}

extern "C" void kernel_launch(void* const* d_in, const int* in_sizes, int n_in,
                              void* d_out, int out_size, void* d_ws, size_t ws_size,
                              hipStream_t stream)
{
    const float* x  = (const float*)d_in[0];
    const float* Wq = (const float*)d_in[1];
    const float* Wk = (const float*)d_in[2];
    const float* Wv = (const float*)d_in[3];

    // ws: q [0,2M) | k [2M,4M) | vT [4M,16M) | xbf [16M,28M) | wall [28M,28.4M)
    unsigned short* qws  = (unsigned short*)d_ws;
    unsigned short* kws  = (unsigned short*)((char*)d_ws + ((size_t)2 << 20));
    unsigned short* vtws = (unsigned short*)((char*)d_ws + ((size_t)4 << 20));
    unsigned short* xbf  = (unsigned short*)((char*)d_ws + ((size_t)16 << 20));
    unsigned short* wall = (unsigned short*)((char*)d_ws + ((size_t)28 << 20));

    xwprep<<<dim3(792), dim3(256), 0, stream>>>(x, Wq, Wk, Wv, xbf, wall);
    qkv_gemm<<<dim3(128, 4), dim3(256), 0, stream>>>(xbf, wall, qws, kws, vtws);
    attn<<<dim3(768), dim3(256), 0, stream>>>(qws, kws, vtws, (float*)d_out);
}

// Round 5
// 138.743 us; speedup vs baseline: 1.0963x; 1.0963x over previous
//
#include <hip/hip_runtime.h>

#define TT 2048
#define DD 384

typedef float f32x4 __attribute__((ext_vector_type(4)));
typedef float f32x16 __attribute__((ext_vector_type(16)));
typedef short s16x8 __attribute__((ext_vector_type(8)));
typedef short s16x2 __attribute__((ext_vector_type(2)));
typedef unsigned int u32x4 __attribute__((ext_vector_type(4)));
typedef unsigned int u32x2 __attribute__((ext_vector_type(2)));

typedef __attribute__((address_space(3))) unsigned char* as3p;
typedef const __attribute__((address_space(1))) unsigned char* as1p;
// HW direct global->LDS copy: 16B/lane x 64 lanes = 1KB per call; LDS dest = uniform base + lane*16.
#define GLLDS(gsrc, ldst) __builtin_amdgcn_global_load_lds((as1p)(gsrc), (as3p)(ldst), 16, 0, 0)

static __device__ __forceinline__ unsigned short f2bf(float f) {
    unsigned int u = __builtin_bit_cast(unsigned int, f);
    u = (u + 0x7fffu + ((u >> 16) & 1u)) >> 16;
    return (unsigned short)u;
}
static __device__ __forceinline__ unsigned int pk2(float a, float b) {
#if __has_builtin(__builtin_amdgcn_cvt_pk_bf16_f32)
    s16x2 t = __builtin_amdgcn_cvt_pk_bf16_f32(a, b);
    return __builtin_bit_cast(unsigned int, t);
#else
    unsigned int ua = __builtin_bit_cast(unsigned int, a);
    unsigned int ub = __builtin_bit_cast(unsigned int, b);
    ua = (ua + 0x7fffu + ((ua >> 16) & 1u)) >> 16;
    ub = (ub + 0x7fffu + ((ub >> 16) & 1u)) & 0xffff0000u;
    return ua | ub;
#endif
}

// ---------------- fused QKV projection GEMM, 128x128 tiles, pk2 fp32->bf16 ----------------
// nb=0 -> q (scaled 1/8, natural [t][64]) | k (PRE-SWIZZLED: within each row, 8-chunk c stored at c^(t&7));
// nb=1..3 -> v transposed vT[e][t], pre-swizzled within each 64-t block (chunk c at c^(e&7)).
// R5: staging conversions use v_cvt_pk_bf16_f32 (1 instr / 2 floats, same RNE rounding as f2bf).
__global__ __launch_bounds__(256, 2) void qkv_gemm(
    const float* __restrict__ x, const float* __restrict__ Wq,
    const float* __restrict__ Wk, const float* __restrict__ Wv,
    unsigned short* __restrict__ qo, unsigned short* __restrict__ ko,
    unsigned short* __restrict__ vto)
{
    __shared__ __align__(16) unsigned short lds[16384];
    const int tid = threadIdx.x;
    const int l   = tid & 63;
    const int w   = tid >> 6;
    const int si  = l & 15;
    const int qq  = l >> 4;
    const int m0  = blockIdx.x * 128;
    const int nb  = blockIdx.y;
    const int wr  = w >> 1, wc = w & 1;

    const int bn = tid & 127;
    const int bk = (tid >> 7) * 16;
    const float* wsrc; int ldw;
    if (nb == 0) { wsrc = (bn < 64) ? (Wq + bn) : (Wk + (bn - 64)); ldw = 64; }
    else         { wsrc = Wv + (nb - 1) * 128 + bn;                 ldw = 384; }

    f32x4 acc[4][4];
    #pragma unroll
    for (int rt = 0; rt < 4; ++rt)
        #pragma unroll
        for (int ct = 0; ct < 4; ++ct) acc[rt][ct] = (f32x4){0.f, 0.f, 0.f, 0.f};

    for (int kt = 0; kt < 12; ++kt) {
        const int k0 = kt * 32;
        #pragma unroll
        for (int i = 0; i < 2; ++i) {
            const int u = tid + 256 * i, r = u >> 2, c = u & 3;
            const float* xp = x + (size_t)(m0 + r) * DD + k0 + c * 8;
            f32x4 x0 = *(const f32x4*)xp;
            f32x4 x1 = *(const f32x4*)(xp + 4);
            u32x4 av = (u32x4){pk2(x0[0], x0[1]), pk2(x0[2], x0[3]),
                               pk2(x1[0], x1[1]), pk2(x1[2], x1[3])};
            *(s16x8*)&lds[r * 32 + ((c ^ (r & 3)) * 8)] = __builtin_bit_cast(s16x8, av);
        }
        {
            float t[16];
            #pragma unroll
            for (int j = 0; j < 16; ++j) t[j] = wsrc[(size_t)(k0 + bk + j) * ldw];
            #pragma unroll
            for (int jj = 0; jj < 2; ++jj) {
                u32x4 bv = (u32x4){pk2(t[jj * 8 + 0], t[jj * 8 + 1]), pk2(t[jj * 8 + 2], t[jj * 8 + 3]),
                                   pk2(t[jj * 8 + 4], t[jj * 8 + 5]), pk2(t[jj * 8 + 6], t[jj * 8 + 7])};
                const int ch = (tid >> 7) * 2 + jj;
                *(s16x8*)&lds[4096 + bn * 32 + ((ch ^ (bn & 3)) * 8)] = __builtin_bit_cast(s16x8, bv);
            }
        }
        __syncthreads();

        s16x8 af[4], bf[4];
        #pragma unroll
        for (int rt = 0; rt < 4; ++rt) {
            const int row = wr * 64 + rt * 16 + si;
            af[rt] = *(const s16x8*)&lds[row * 32 + ((qq ^ (row & 3)) * 8)];
        }
        #pragma unroll
        for (int ct = 0; ct < 4; ++ct) {
            const int col = wc * 64 + ct * 16 + si;
            bf[ct] = *(const s16x8*)&lds[4096 + col * 32 + ((qq ^ (col & 3)) * 8)];
        }
        #pragma unroll
        for (int rt = 0; rt < 4; ++rt)
            #pragma unroll
            for (int ct = 0; ct < 4; ++ct)
                acc[rt][ct] = __builtin_amdgcn_mfma_f32_16x16x32_bf16(af[rt], bf[ct], acc[rt][ct], 0, 0, 0);
        __syncthreads();
    }

    if (nb == 0) {
        if (wc == 0) {  // q: natural layout, fold 1/sqrt(K)
            #pragma unroll
            for (int rt = 0; rt < 4; ++rt)
                #pragma unroll
                for (int ct = 0; ct < 4; ++ct)
                    #pragma unroll
                    for (int r = 0; r < 4; ++r) {
                        const int m = m0 + wr * 64 + rt * 16 + qq * 4 + r;
                        qo[(size_t)m * 64 + ct * 16 + si] = f2bf(acc[rt][ct][r] * 0.125f);
                    }
        } else {        // k: pre-swizzled (chunk c -> c ^ (t&7))
            #pragma unroll
            for (int rt = 0; rt < 4; ++rt)
                #pragma unroll
                for (int ct = 0; ct < 4; ++ct)
                    #pragma unroll
                    for (int r = 0; r < 4; ++r) {
                        const int m = m0 + wr * 64 + rt * 16 + qq * 4 + r;
                        const int col = ct * 16 + si;
                        ko[(size_t)m * 64 + (((col >> 3) ^ (m & 7)) * 8) + (col & 7)] = f2bf(acc[rt][ct][r]);
                    }
        }
    } else {
        #pragma unroll
        for (int rt = 0; rt < 4; ++rt)
            #pragma unroll
            for (int ct = 0; ct < 4; ++ct)
                #pragma unroll
                for (int r = 0; r < 4; ++r) {
                    const int m = wr * 64 + rt * 16 + qq * 4 + r;
                    const int n = wc * 64 + ct * 16 + si;
                    lds[n * 128 + (((m >> 3) ^ (n & 7)) * 8) + (m & 7)] = f2bf(acc[rt][ct][r]);
                }
        __syncthreads();
        const int bbat = m0 >> 11, t0 = m0 & 2047;
        #pragma unroll
        for (int i = 0; i < 8; ++i) {
            const int u = tid + 256 * i, n = u >> 4, mc = u & 15;
            s16x8 v = *(const s16x8*)&lds[n * 128 + ((mc ^ (n & 7)) * 8)];
            *(s16x8*)&vto[((size_t)bbat * DD + ((nb - 1) * 128 + n)) * TT
                          + t0 + (mc >> 3) * 64 + (((mc & 7) ^ (n & 7)) * 8)] = v;
        }
    }
}

// ---------------- fused causal attention, P-computed-once, pipelined P, 256-thr ----------------
// R3 structure (proven 50.6us) + R5 micro-fixes: (a) pack via v_permlane32_swap_b32 — one swap
// yields BOTH {d0.lo||d2.lo} and {d0.hi||d2.hi}, replacing 4 shfl_xor + 8 selects (no divergence,
// no LDS shuffle); (b) s_setprio(1) around the QK and PV MFMA clusters (m191: helps attn when
// co-resident blocks sit at different phases).
__global__ __launch_bounds__(256, 2) void attn(
    const unsigned short* __restrict__ qg, const unsigned short* __restrict__ kg,
    const unsigned short* __restrict__ vg, float* __restrict__ out)
{
    // ush map: kl [0,8192) = 2 x [64 t][64] | vl [8192,32768) = 3 x [128 e][64 t]
    //          pl [32768,40960) = 2 x [2 qh][2 ss][a0:512|a1:512] | stL overlays pl after loop
    __shared__ __align__(16) unsigned short lds[40960];

    const int tid = threadIdx.x;
    const int l   = tid & 63;
    const int w   = tid >> 6;    // 0..3
    const int qh  = w >> 1;      // 32-row q half
    const int eg  = w & 1;       // 64-col e group; doubles as produced s-subtile ss
    const int lo  = l & 31;
    const int hi  = l >> 5;

    const int g    = blockIdx.x;          // 0..767
    const int bb   = g & 7;
    const int rest = g >> 3;              // 0..95
    const int eh   = rest % 3;
    const int q2   = 31 - rest / 3;       // descending work (LPT)
    const int q0   = q2 * 64;
    const int e0   = eh * 128;
    const int qrow = q0 + qh * 32 + lo;

    // Q as B-operand frags (pre-scaled 1/8, natural layout)
    s16x8 qf[4];
    {
        const unsigned short* qp = qg + ((size_t)bb * TT + qrow) * 64;
        #pragma unroll
        for (int st = 0; st < 4; ++st) qf[st] = *(const s16x8*)(qp + st * 16 + hi * 8);
    }

    f32x16 o[2];
    #pragma unroll
    for (int et = 0; et < 2; ++et)
        #pragma unroll
        for (int r = 0; r < 16; ++r) o[et][r] = 0.f;
    float lp = 0.f;

    const unsigned short* kbase = kg + (size_t)bb * TT * 64;
    const unsigned short* vbase = vg + ((size_t)bb * DD + e0) * TT;

    // staging: K 8 chunks (2/wave) + V 16 chunks (4/wave), 1KB each
    #define STAGE(IT, KB, VB)                                                              \
    {                                                                                      \
        GLLDS(kbase + (size_t)(IT) * 4096 + (2 * w) * 512 + l * 8,                         \
              &lds[(KB) * 4096 + (2 * w) * 512]);                                          \
        GLLDS(kbase + (size_t)(IT) * 4096 + (2 * w + 1) * 512 + l * 8,                     \
              &lds[(KB) * 4096 + (2 * w + 1) * 512]);                                      \
        _Pragma("unroll")                                                                  \
        for (int c3 = 0; c3 < 4; ++c3) {                                                   \
            const int rg = 4 * w + c3;                                                     \
            GLLDS(vbase + (size_t)(rg * 8 + (l >> 3)) * TT + (IT) * 64 + (l & 7) * 8,      \
                  &lds[8192 + (VB) * 8192 + rg * 512]);                                    \
        }                                                                                  \
    }

    // PV consume of s-tile JT from vl[VB], pl[PB]
    #define PVSTEP(VB, PB)                                                                 \
    {                                                                                      \
        __builtin_amdgcn_s_setprio(1);                                                     \
        _Pragma("unroll")                                                                  \
        for (int ss = 0; ss < 2; ++ss) {                                                   \
            s16x8 a0 = *(const s16x8*)&lds[32768 + (PB) * 4096 + (qh * 2 + ss) * 1024 + l * 8];       \
            s16x8 a1 = *(const s16x8*)&lds[32768 + (PB) * 4096 + (qh * 2 + ss) * 1024 + 512 + l * 8]; \
            _Pragma("unroll")                                                              \
            for (int et = 0; et < 2; ++et) {                                               \
                const int el = eg * 64 + et * 32 + lo;                                     \
                const int vbse = 8192 + (VB) * 8192 + el * 64;                             \
                s16x8 v0 = *(const s16x8*)&lds[vbse + (((ss * 4 + hi) ^ (el & 7)) * 8)];   \
                o[et] = __builtin_amdgcn_mfma_f32_32x32x16_bf16(a0, v0, o[et], 0, 0, 0);   \
                s16x8 v1 = *(const s16x8*)&lds[vbse + (((ss * 4 + 2 + hi) ^ (el & 7)) * 8)]; \
                o[et] = __builtin_amdgcn_mfma_f32_32x32x16_bf16(a1, v1, o[et], 0, 0, 0);   \
            }                                                                              \
        }                                                                                  \
        __builtin_amdgcn_s_setprio(0);                                                     \
    }

    STAGE(0, 0, 0);   // prologue: tile 0 -> kl0 / vl0

    int vi = 0, vn = 1;   // vl index of tile it, it+1 (mod 3); tile it-1 sits at the third slot
    for (int it = 0; it <= q2; ++it) {
        const int kb = it & 1;
        __syncthreads();   // vmcnt(0)+barrier: staging for tile it complete; pl[kb] free to overwrite

        if (it < q2) STAGE(it + 1, 1 - kb, vn);   // in flight during compute

        // ---- produce P-subtile (qh, ss=eg) of tile it -> pl[kb] ----
        {
            f32x16 sa;
            #pragma unroll
            for (int r = 0; r < 16; ++r) sa[r] = 0.f;
            __builtin_amdgcn_s_setprio(1);
            #pragma unroll
            for (int st = 0; st < 4; ++st) {
                s16x8 kf = *(const s16x8*)&lds[kb * 4096 + (eg * 32 + lo) * 64 + (((st * 2 + hi) ^ (lo & 7)) * 8)];
                sa = __builtin_amdgcn_mfma_f32_32x32x16_bf16(kf, qf[st], sa, 0, 0, 0);
            }
            __builtin_amdgcn_s_setprio(0);
            const bool mb = (it == q2);
            float pv[16];
            #pragma unroll
            for (int r = 0; r < 16; ++r) {
                float e = __expf(sa[r]);
                if (mb) {
                    const int srow = it * 64 + eg * 32 + (r & 3) + 8 * (r >> 2) + 4 * hi;
                    if (srow > qrow) e = 0.f;
                }
                pv[r] = e;
                lp += e;
            }
            unsigned int d0 = pk2(pv[0], pv[1]),   d1 = pk2(pv[2], pv[3]);
            unsigned int d2 = pk2(pv[4], pv[5]),   d3 = pk2(pv[6], pv[7]);
            unsigned int d4 = pk2(pv[8], pv[9]),   d5 = pk2(pv[10], pv[11]);
            unsigned int d6 = pk2(pv[12], pv[13]), d7 = pk2(pv[14], pv[15]);
            u32x4 fa0, fa1;
#if __has_builtin(__builtin_amdgcn_permlane32_swap)
            {   // one swap yields word j (lo||lo) AND word j+2 (hi||hi) — replaces shfl+selects
                u32x2 s02 = __builtin_bit_cast(u32x2, __builtin_amdgcn_permlane32_swap(d0, d2, false, false));
                u32x2 s13 = __builtin_bit_cast(u32x2, __builtin_amdgcn_permlane32_swap(d1, d3, false, false));
                u32x2 s46 = __builtin_bit_cast(u32x2, __builtin_amdgcn_permlane32_swap(d4, d6, false, false));
                u32x2 s57 = __builtin_bit_cast(u32x2, __builtin_amdgcn_permlane32_swap(d5, d7, false, false));
                fa0 = (u32x4){s02[0], s13[0], s02[1], s13[1]};
                fa1 = (u32x4){s46[0], s57[0], s46[1], s57[1]};
            }
#else
            {
                unsigned int sA0 = hi ? d0 : d2, sA1 = hi ? d1 : d3;
                unsigned int rA0 = (unsigned int)__shfl_xor((int)sA0, 32);
                unsigned int rA1 = (unsigned int)__shfl_xor((int)sA1, 32);
                fa0 = hi ? (u32x4){rA0, rA1, d2, d3} : (u32x4){d0, d1, rA0, rA1};
                unsigned int sB0 = hi ? d4 : d6, sB1 = hi ? d5 : d7;
                unsigned int rB0 = (unsigned int)__shfl_xor((int)sB0, 32);
                unsigned int rB1 = (unsigned int)__shfl_xor((int)sB1, 32);
                fa1 = hi ? (u32x4){rB0, rB1, d6, d7} : (u32x4){d4, d5, rB0, rB1};
            }
#endif
            *(s16x8*)&lds[32768 + kb * 4096 + (qh * 2 + eg) * 1024 + l * 8]       = __builtin_bit_cast(s16x8, fa0);
            *(s16x8*)&lds[32768 + kb * 4096 + (qh * 2 + eg) * 1024 + 512 + l * 8] = __builtin_bit_cast(s16x8, fa1);
        }

        // ---- consume P of tile it-1 (written last iter; visible since barrier) ----
        if (it > 0) {
            const int vp = (vi == 0) ? 2 : vi - 1;
            PVSTEP(vp, 1 - kb);
        }

        vi = vn; vn = (vn == 2) ? 0 : vn + 1;
    }
    __syncthreads();           // last pl writes visible to all waves
    {
        const int vlast = (vi == 0) ? 2 : vi - 1;   // vl slot of tile q2
        PVSTEP(vlast, q2 & 1);
    }
    __syncthreads();           // all PV reads of pl done before stL overlays it

    // row sums: wave (qh, eg) holds lp for rows qh*32+lo over s-subtiles ss=eg
    float* stL = (float*)&lds[32768];   // [2 qh][2 ss][32]
    lp += __shfl_xor(lp, 32);
    if (hi == 0) stL[(qh * 2 + eg) * 32 + lo] = lp;
    __syncthreads();

    #pragma unroll
    for (int et = 0; et < 2; ++et)
        #pragma unroll
        for (int r = 0; r < 16; ++r) {
            const int rloc = (r & 3) + 8 * (r >> 2) + 4 * hi;
            const float linv = 1.f / (stL[qh * 64 + rloc] + stL[qh * 64 + 32 + rloc]);
            out[((size_t)bb * TT + q0 + qh * 32 + rloc) * DD + e0 + eg * 64 + et * 32 + lo]
                = o[et][r] * linv;
        }
    #undef STAGE
    #undef PVSTEP
}

extern "C" void kernel_launch(void* const* d_in, const int* in_sizes, int n_in,
                              void* d_out, int out_size, void* d_ws, size_t ws_size,
                              hipStream_t stream)
{
    const float* x  = (const float*)d_in[0];
    const float* Wq = (const float*)d_in[1];
    const float* Wk = (const float*)d_in[2];
    const float* Wv = (const float*)d_in[3];

    // ws: q [0,2M) | k [2M,4M) | vT [4M,16M)
    unsigned short* qws  = (unsigned short*)d_ws;
    unsigned short* kws  = (unsigned short*)((char*)d_ws + ((size_t)2 << 20));
    unsigned short* vtws = (unsigned short*)((char*)d_ws + ((size_t)4 << 20));

    qkv_gemm<<<dim3(128, 4), dim3(256), 0, stream>>>(x, Wq, Wk, Wv, qws, kws, vtws);
    attn<<<dim3(768), dim3(256), 0, stream>>>(qws, kws, vtws, (float*)d_out);
}

// Round 6
// 133.379 us; speedup vs baseline: 1.1404x; 1.0402x over previous
//
#include <hip/hip_runtime.h>

#define TT 2048
#define DD 384

typedef float f32x4 __attribute__((ext_vector_type(4)));
typedef float f32x16 __attribute__((ext_vector_type(16)));
typedef short s16x8 __attribute__((ext_vector_type(8)));
typedef short s16x2 __attribute__((ext_vector_type(2)));
typedef unsigned int u32x4 __attribute__((ext_vector_type(4)));
typedef unsigned int u32x2 __attribute__((ext_vector_type(2)));

typedef __attribute__((address_space(3))) unsigned char* as3p;
typedef const __attribute__((address_space(1))) unsigned char* as1p;
// HW direct global->LDS copy: 16B/lane x 64 lanes = 1KB per call; LDS dest = uniform base + lane*16.
#define GLLDS(gsrc, ldst) __builtin_amdgcn_global_load_lds((as1p)(gsrc), (as3p)(ldst), 16, 0, 0)

static __device__ __forceinline__ unsigned short f2bf(float f) {
    unsigned int u = __builtin_bit_cast(unsigned int, f);
    u = (u + 0x7fffu + ((u >> 16) & 1u)) >> 16;
    return (unsigned short)u;
}
static __device__ __forceinline__ unsigned int pk2(float a, float b) {
#if __has_builtin(__builtin_amdgcn_cvt_pk_bf16_f32)
    s16x2 t = __builtin_amdgcn_cvt_pk_bf16_f32(a, b);
    return __builtin_bit_cast(unsigned int, t);
#else
    unsigned int ua = __builtin_bit_cast(unsigned int, a);
    unsigned int ub = __builtin_bit_cast(unsigned int, b);
    ua = (ua + 0x7fffu + ((ua >> 16) & 1u)) >> 16;
    ub = (ub + 0x7fffu + ((ub >> 16) & 1u)) & 0xffff0000u;
    return ua | ub;
#endif
}

// ---------------- fused QKV projection GEMM, 128x128 tiles, pk2 fp32->bf16 ----------------
// nb=0 -> q (scaled 1/8, natural [t][64]) | k (PRE-SWIZZLED: within each row, 8-chunk c stored at c^(t&7));
// nb=1..3 -> v transposed vT[e][t], pre-swizzled within each 64-t block (chunk c at c^(e&7)).
__global__ __launch_bounds__(256, 2) void qkv_gemm(
    const float* __restrict__ x, const float* __restrict__ Wq,
    const float* __restrict__ Wk, const float* __restrict__ Wv,
    unsigned short* __restrict__ qo, unsigned short* __restrict__ ko,
    unsigned short* __restrict__ vto)
{
    __shared__ __align__(16) unsigned short lds[16384];
    const int tid = threadIdx.x;
    const int l   = tid & 63;
    const int w   = tid >> 6;
    const int si  = l & 15;
    const int qq  = l >> 4;
    const int m0  = blockIdx.x * 128;
    const int nb  = blockIdx.y;
    const int wr  = w >> 1, wc = w & 1;

    const int bn = tid & 127;
    const int bk = (tid >> 7) * 16;
    const float* wsrc; int ldw;
    if (nb == 0) { wsrc = (bn < 64) ? (Wq + bn) : (Wk + (bn - 64)); ldw = 64; }
    else         { wsrc = Wv + (nb - 1) * 128 + bn;                 ldw = 384; }

    f32x4 acc[4][4];
    #pragma unroll
    for (int rt = 0; rt < 4; ++rt)
        #pragma unroll
        for (int ct = 0; ct < 4; ++ct) acc[rt][ct] = (f32x4){0.f, 0.f, 0.f, 0.f};

    for (int kt = 0; kt < 12; ++kt) {
        const int k0 = kt * 32;
        #pragma unroll
        for (int i = 0; i < 2; ++i) {
            const int u = tid + 256 * i, r = u >> 2, c = u & 3;
            const float* xp = x + (size_t)(m0 + r) * DD + k0 + c * 8;
            f32x4 x0 = *(const f32x4*)xp;
            f32x4 x1 = *(const f32x4*)(xp + 4);
            u32x4 av = (u32x4){pk2(x0[0], x0[1]), pk2(x0[2], x0[3]),
                               pk2(x1[0], x1[1]), pk2(x1[2], x1[3])};
            *(s16x8*)&lds[r * 32 + ((c ^ (r & 3)) * 8)] = __builtin_bit_cast(s16x8, av);
        }
        {
            float t[16];
            #pragma unroll
            for (int j = 0; j < 16; ++j) t[j] = wsrc[(size_t)(k0 + bk + j) * ldw];
            #pragma unroll
            for (int jj = 0; jj < 2; ++jj) {
                u32x4 bv = (u32x4){pk2(t[jj * 8 + 0], t[jj * 8 + 1]), pk2(t[jj * 8 + 2], t[jj * 8 + 3]),
                                   pk2(t[jj * 8 + 4], t[jj * 8 + 5]), pk2(t[jj * 8 + 6], t[jj * 8 + 7])};
                const int ch = (tid >> 7) * 2 + jj;
                *(s16x8*)&lds[4096 + bn * 32 + ((ch ^ (bn & 3)) * 8)] = __builtin_bit_cast(s16x8, bv);
            }
        }
        __syncthreads();

        s16x8 af[4], bf[4];
        #pragma unroll
        for (int rt = 0; rt < 4; ++rt) {
            const int row = wr * 64 + rt * 16 + si;
            af[rt] = *(const s16x8*)&lds[row * 32 + ((qq ^ (row & 3)) * 8)];
        }
        #pragma unroll
        for (int ct = 0; ct < 4; ++ct) {
            const int col = wc * 64 + ct * 16 + si;
            bf[ct] = *(const s16x8*)&lds[4096 + col * 32 + ((qq ^ (col & 3)) * 8)];
        }
        #pragma unroll
        for (int rt = 0; rt < 4; ++rt)
            #pragma unroll
            for (int ct = 0; ct < 4; ++ct)
                acc[rt][ct] = __builtin_amdgcn_mfma_f32_16x16x32_bf16(af[rt], bf[ct], acc[rt][ct], 0, 0, 0);
        __syncthreads();
    }

    if (nb == 0) {
        if (wc == 0) {  // q: natural layout, fold 1/sqrt(K)
            #pragma unroll
            for (int rt = 0; rt < 4; ++rt)
                #pragma unroll
                for (int ct = 0; ct < 4; ++ct)
                    #pragma unroll
                    for (int r = 0; r < 4; ++r) {
                        const int m = m0 + wr * 64 + rt * 16 + qq * 4 + r;
                        qo[(size_t)m * 64 + ct * 16 + si] = f2bf(acc[rt][ct][r] * 0.125f);
                    }
        } else {        // k: pre-swizzled (chunk c -> c ^ (t&7))
            #pragma unroll
            for (int rt = 0; rt < 4; ++rt)
                #pragma unroll
                for (int ct = 0; ct < 4; ++ct)
                    #pragma unroll
                    for (int r = 0; r < 4; ++r) {
                        const int m = m0 + wr * 64 + rt * 16 + qq * 4 + r;
                        const int col = ct * 16 + si;
                        ko[(size_t)m * 64 + (((col >> 3) ^ (m & 7)) * 8) + (col & 7)] = f2bf(acc[rt][ct][r]);
                    }
        }
    } else {
        #pragma unroll
        for (int rt = 0; rt < 4; ++rt)
            #pragma unroll
            for (int ct = 0; ct < 4; ++ct)
                #pragma unroll
                for (int r = 0; r < 4; ++r) {
                    const int m = wr * 64 + rt * 16 + qq * 4 + r;
                    const int n = wc * 64 + ct * 16 + si;
                    lds[n * 128 + (((m >> 3) ^ (n & 7)) * 8) + (m & 7)] = f2bf(acc[rt][ct][r]);
                }
        __syncthreads();
        const int bbat = m0 >> 11, t0 = m0 & 2047;
        #pragma unroll
        for (int i = 0; i < 8; ++i) {
            const int u = tid + 256 * i, n = u >> 4, mc = u & 15;
            s16x8 v = *(const s16x8*)&lds[n * 128 + ((mc ^ (n & 7)) * 8)];
            *(s16x8*)&vto[((size_t)bbat * DD + ((nb - 1) * 128 + n)) * TT
                          + t0 + (mc >> 3) * 64 + (((mc & 7) ^ (n & 7)) * 8)] = v;
        }
    }
}

// ---------------- fused causal attention R6: constant-work paired blocks, 12 waves ----------------
// Block = (bb, eh: 192 e-cols, PAIR of q-tiles (q2, 31-q2) done sequentially -> 33 iters/block,
// CONSTANT: 256 uniform blocks on 256 CUs, placement-independent balance). 768 thr = 12 waves
// (qh 2 x eu 6): every wave consumes one 32-e-col unit (4 PV MFMA/iter, per-wave load == R5);
// waves 0-3 additionally produce P subtile (qh, ss) — same per-wave produce as R5, but e-dup
// drops 3x->2x, V staged bytes 2/3, barrier count per CU 49.5->33, 12 waves/CU vs 8.
// Same lag-1 P pipeline + single barrier/iter + V tbuf + K/P dbuf as R3/R5 (proven).
__global__ __launch_bounds__(768, 3) void attn(
    const unsigned short* __restrict__ qg, const unsigned short* __restrict__ kg,
    const unsigned short* __restrict__ vg, float* __restrict__ out)
{
    // ush map: kl [0,8192) = 2 x [64 t][64] | vl [8192,45056) = 3 x [192 e][64 t]
    //          pl [45056,53248) = 2 x [2 qh][2 ss][a0:512|a1:512] | stL overlays kl after loop
    __shared__ __align__(16) unsigned short lds[53248];

    const int tid = threadIdx.x;
    const int l   = tid & 63;
    const int w   = tid >> 6;     // 0..11
    const int qh  = w & 1;        // 32-row q half (within the 64-row tile)
    const int eu  = w >> 1;       // 0..5: 32-col e unit (consume role)
    const bool isprod = (w < 4);  // waves 0-3 produce subtile (qh, ss=eu)
    const int lo  = l & 31;
    const int hi  = l >> 5;

    const int g  = blockIdx.x;    // 0..255
    const int bb = g & 7;
    const int eh = (g >> 3) & 1;
    const int pr = g >> 4;        // 0..15 pair id
    const int e0 = eh * 192;

    const unsigned short* kbase = kg + (size_t)bb * TT * 64;
    const unsigned short* vbase = vg + ((size_t)bb * DD + e0) * TT;

    // staging: K 8 chunks by produce waves (2 each); V 24 chunks by waves 4..11 (3 each)
    #define STAGE(IT, KB, VB)                                                              \
    {                                                                                      \
        if (isprod) {                                                                      \
            GLLDS(kbase + (size_t)(IT) * 4096 + (2 * w) * 512 + l * 8,                     \
                  &lds[(KB) * 4096 + (2 * w) * 512]);                                      \
            GLLDS(kbase + (size_t)(IT) * 4096 + (2 * w + 1) * 512 + l * 8,                 \
                  &lds[(KB) * 4096 + (2 * w + 1) * 512]);                                  \
        } else {                                                                           \
            _Pragma("unroll")                                                              \
            for (int c3 = 0; c3 < 3; ++c3) {                                               \
                const int rg = 3 * (w - 4) + c3;                                           \
                GLLDS(vbase + (size_t)(rg * 8 + (l >> 3)) * TT + (IT) * 64 + (l & 7) * 8,  \
                      &lds[8192 + (VB) * 12288 + rg * 512]);                               \
            }                                                                              \
        }                                                                                  \
    }

    // PV consume of one s-tile from vl[VB], pl[PB]: this wave's (qh, eu) 32q x 32e block
    #define PVSTEP(VB, PB)                                                                 \
    {                                                                                      \
        __builtin_amdgcn_s_setprio(1);                                                     \
        _Pragma("unroll")                                                                  \
        for (int ss = 0; ss < 2; ++ss) {                                                   \
            const int pbse = 45056 + (PB) * 4096 + (qh * 2 + ss) * 1024;                   \
            s16x8 a0 = *(const s16x8*)&lds[pbse + l * 8];                                  \
            s16x8 a1 = *(const s16x8*)&lds[pbse + 512 + l * 8];                            \
            const int el = eu * 32 + lo;                                                   \
            const int vbse = 8192 + (VB) * 12288 + el * 64;                                \
            s16x8 v0 = *(const s16x8*)&lds[vbse + (((ss * 4 + hi) ^ (el & 7)) * 8)];       \
            o = __builtin_amdgcn_mfma_f32_32x32x16_bf16(a0, v0, o, 0, 0, 0);               \
            s16x8 v1 = *(const s16x8*)&lds[vbse + (((ss * 4 + 2 + hi) ^ (el & 7)) * 8)];   \
            o = __builtin_amdgcn_mfma_f32_32x32x16_bf16(a1, v1, o, 0, 0, 0);               \
        }                                                                                  \
        __builtin_amdgcn_s_setprio(0);                                                     \
    }

    for (int hf = 0; hf < 2; ++hf) {
        const int q2 = hf ? pr : 31 - pr;      // heavy tile first, then its complement
        const int q0 = q2 * 64;
        const int qrow = q0 + qh * 32 + lo;

        // Q as B-operand frags (pre-scaled 1/8, natural layout) — produce waves only
        s16x8 qf[4];
        if (isprod) {
            const unsigned short* qp = qg + ((size_t)bb * TT + qrow) * 64;
            #pragma unroll
            for (int st = 0; st < 4; ++st) qf[st] = *(const s16x8*)(qp + st * 16 + hi * 8);
        }

        f32x16 o;
        #pragma unroll
        for (int r = 0; r < 16; ++r) o[r] = 0.f;
        float lp = 0.f;

        STAGE(0, 0, 0);   // prologue: tile 0 -> kl0 / vl0

        int vi = 0, vn = 1;   // vl slot of tile it, it+1 (mod 3); tile it-1 sits at the third slot
        for (int it = 0; it <= q2; ++it) {
            const int kb = it & 1;
            __syncthreads();   // vmcnt(0)+barrier: staging for tile it complete; pl[kb] free

            if (it < q2) STAGE(it + 1, 1 - kb, vn);   // in flight during compute

            if (isprod) {   // ---- produce P-subtile (qh, ss=eu) of tile it -> pl[kb] ----
                f32x16 sa;
                #pragma unroll
                for (int r = 0; r < 16; ++r) sa[r] = 0.f;
                __builtin_amdgcn_s_setprio(1);
                #pragma unroll
                for (int st = 0; st < 4; ++st) {
                    s16x8 kf = *(const s16x8*)&lds[kb * 4096 + (eu * 32 + lo) * 64 + (((st * 2 + hi) ^ (lo & 7)) * 8)];
                    sa = __builtin_amdgcn_mfma_f32_32x32x16_bf16(kf, qf[st], sa, 0, 0, 0);
                }
                __builtin_amdgcn_s_setprio(0);
                const bool mb = (it == q2);
                float pv[16];
                #pragma unroll
                for (int r = 0; r < 16; ++r) {
                    float e = __expf(sa[r]);
                    if (mb) {
                        const int srow = it * 64 + eu * 32 + (r & 3) + 8 * (r >> 2) + 4 * hi;
                        if (srow > qrow) e = 0.f;
                    }
                    pv[r] = e;
                    lp += e;
                }
                unsigned int d0 = pk2(pv[0], pv[1]),   d1 = pk2(pv[2], pv[3]);
                unsigned int d2 = pk2(pv[4], pv[5]),   d3 = pk2(pv[6], pv[7]);
                unsigned int d4 = pk2(pv[8], pv[9]),   d5 = pk2(pv[10], pv[11]);
                unsigned int d6 = pk2(pv[12], pv[13]), d7 = pk2(pv[14], pv[15]);
                u32x4 fa0, fa1;
#if __has_builtin(__builtin_amdgcn_permlane32_swap)
                {
                    u32x2 s02 = __builtin_bit_cast(u32x2, __builtin_amdgcn_permlane32_swap(d0, d2, false, false));
                    u32x2 s13 = __builtin_bit_cast(u32x2, __builtin_amdgcn_permlane32_swap(d1, d3, false, false));
                    u32x2 s46 = __builtin_bit_cast(u32x2, __builtin_amdgcn_permlane32_swap(d4, d6, false, false));
                    u32x2 s57 = __builtin_bit_cast(u32x2, __builtin_amdgcn_permlane32_swap(d5, d7, false, false));
                    fa0 = (u32x4){s02[0], s13[0], s02[1], s13[1]};
                    fa1 = (u32x4){s46[0], s57[0], s46[1], s57[1]};
                }
#else
                {
                    unsigned int sA0 = hi ? d0 : d2, sA1 = hi ? d1 : d3;
                    unsigned int rA0 = (unsigned int)__shfl_xor((int)sA0, 32);
                    unsigned int rA1 = (unsigned int)__shfl_xor((int)sA1, 32);
                    fa0 = hi ? (u32x4){rA0, rA1, d2, d3} : (u32x4){d0, d1, rA0, rA1};
                    unsigned int sB0 = hi ? d4 : d6, sB1 = hi ? d5 : d7;
                    unsigned int rB0 = (unsigned int)__shfl_xor((int)sB0, 32);
                    unsigned int rB1 = (unsigned int)__shfl_xor((int)sB1, 32);
                    fa1 = hi ? (u32x4){rB0, rB1, d6, d7} : (u32x4){d4, d5, rB0, rB1};
                }
#endif
                *(s16x8*)&lds[45056 + kb * 4096 + (qh * 2 + eu) * 1024 + l * 8]       = __builtin_bit_cast(s16x8, fa0);
                *(s16x8*)&lds[45056 + kb * 4096 + (qh * 2 + eu) * 1024 + 512 + l * 8] = __builtin_bit_cast(s16x8, fa1);
            }

            // ---- consume P of tile it-1 (written last iter; visible since barrier) ----
            if (it > 0) {
                const int vp = (vi == 0) ? 2 : vi - 1;
                PVSTEP(vp, 1 - kb);
            }

            vi = vn; vn = (vn == 2) ? 0 : vn + 1;
        }
        __syncthreads();           // last pl writes visible to all waves; kl dead -> stL may overlay
        {
            const int vlast = (vi == 0) ? 2 : vi - 1;   // vl slot of tile q2
            PVSTEP(vlast, q2 & 1);
        }
        if (isprod) {              // row totals -> stL (overlays dead kl region)
            float lt = lp + __shfl_xor(lp, 32);
            if (hi == 0) ((float*)lds)[(qh * 2 + eu) * 32 + lo] = lt;
        }
        __syncthreads();

        // epilogue: every wave writes its (qh, eu) 32x32 O block, normalized
        {
            const float* stL = (const float*)lds;   // [2 qh][2 ss][32]
            #pragma unroll
            for (int r = 0; r < 16; ++r) {
                const int rloc = (r & 3) + 8 * (r >> 2) + 4 * hi;
                const float linv = 1.f / (stL[(qh * 2) * 32 + rloc] + stL[(qh * 2 + 1) * 32 + rloc]);
                out[((size_t)bb * TT + q0 + qh * 32 + rloc) * DD + e0 + eu * 32 + lo]
                    = o[r] * linv;
            }
        }
        __syncthreads();           // all stL reads + vl/pl reads done before next half re-stages
    }
    #undef STAGE
    #undef PVSTEP
}

extern "C" void kernel_launch(void* const* d_in, const int* in_sizes, int n_in,
                              void* d_out, int out_size, void* d_ws, size_t ws_size,
                              hipStream_t stream)
{
    const float* x  = (const float*)d_in[0];
    const float* Wq = (const float*)d_in[1];
    const float* Wk = (const float*)d_in[2];
    const float* Wv = (const float*)d_in[3];

    // ws: q [0,2M) | k [2M,4M) | vT [4M,16M)
    unsigned short* qws  = (unsigned short*)d_ws;
    unsigned short* kws  = (unsigned short*)((char*)d_ws + ((size_t)2 << 20));
    unsigned short* vtws = (unsigned short*)((char*)d_ws + ((size_t)4 << 20));

    qkv_gemm<<<dim3(128, 4), dim3(256), 0, stream>>>(x, Wq, Wk, Wv, qws, kws, vtws);
    attn<<<dim3(256), dim3(768), 0, stream>>>(qws, kws, vtws, (float*)d_out);
}